// Round 1
// baseline (219.049 us; speedup 1.0000x reference)
//
#include <hip/hip_runtime.h>
#include <hip/hip_bf16.h>

#define BDIM 8192
#define DDIM 256

typedef __attribute__((ext_vector_type(8))) short  s16x8;   // 8 x bf16 (4 VGPRs)
typedef __attribute__((ext_vector_type(4))) float  f32x4;   // MFMA accumulator

// ---------------------------------------------------------------------------
// init: zero the two accumulators in workspace
// ---------------------------------------------------------------------------
__global__ void init_accum(float* accum) {
    if (threadIdx.x < 2) accum[threadIdx.x] = 0.0f;
}

// ---------------------------------------------------------------------------
// Kernel A: per-row stats.
//   - triplet contribution: relu(||a-p+eps|| - ||a-n+eps|| + margin) -> atomicAdd accum[0]
//   - a_hat (bf16) written to workspace
// One wave (64 lanes) per row; each lane handles 4 contiguous floats.
// ---------------------------------------------------------------------------
__global__ __launch_bounds__(256) void row_stats(
    const float* __restrict__ A, const float* __restrict__ P,
    const float* __restrict__ N, __hip_bfloat16* __restrict__ Ahat,
    float* __restrict__ accum)
{
    const int wave = threadIdx.x >> 6;
    const int lane = threadIdx.x & 63;
    const int row  = blockIdx.x * 4 + wave;

    const float4 a = *(reinterpret_cast<const float4*>(A + (size_t)row * DDIM) + lane);
    const float4 p = *(reinterpret_cast<const float4*>(P + (size_t)row * DDIM) + lane);
    const float4 n = *(reinterpret_cast<const float4*>(N + (size_t)row * DDIM) + lane);

    float sa = a.x*a.x + a.y*a.y + a.z*a.z + a.w*a.w;

    float d0 = a.x - p.x + 1e-6f, d1 = a.y - p.y + 1e-6f;
    float d2 = a.z - p.z + 1e-6f, d3 = a.w - p.w + 1e-6f;
    float sp = d0*d0 + d1*d1 + d2*d2 + d3*d3;

    d0 = a.x - n.x + 1e-6f; d1 = a.y - n.y + 1e-6f;
    d2 = a.z - n.z + 1e-6f; d3 = a.w - n.w + 1e-6f;
    float sn = d0*d0 + d1*d1 + d2*d2 + d3*d3;

    // butterfly reduce across the 64-lane wave (all lanes get the totals)
    #pragma unroll
    for (int off = 32; off > 0; off >>= 1) {
        sa += __shfl_xor(sa, off);
        sp += __shfl_xor(sp, off);
        sn += __shfl_xor(sn, off);
    }

    const float norm = sqrtf(sa);
    const float inv  = 1.0f / fmaxf(norm, 1e-8f);

    // write a_hat as bf16 (4 elems / lane, 8B store)
    __hip_bfloat16 h[4];
    h[0] = __float2bfloat16(a.x * inv);
    h[1] = __float2bfloat16(a.y * inv);
    h[2] = __float2bfloat16(a.z * inv);
    h[3] = __float2bfloat16(a.w * inv);
    *reinterpret_cast<ushort2*>(Ahat + (size_t)row * DDIM + lane * 4) =
        *reinterpret_cast<ushort2*>(&h[0]);
    *reinterpret_cast<ushort2*>(Ahat + (size_t)row * DDIM + lane * 4 + 2) =
        *reinterpret_cast<ushort2*>(&h[2]);

    if (lane == 0) {
        const float t = fmaxf(sqrtf(sp) - sqrtf(sn) + 0.2f, 0.0f);
        atomicAdd(&accum[0], t);
    }
}

// ---------------------------------------------------------------------------
// Kernel B: 128x128 tile of cos = a_hat @ a_hat^T via bf16 MFMA, fused with
// sum of (cos - S)^2 -> atomicAdd accum[1].
// Block = 256 threads = 4 waves in 2x2; each wave computes a 64x64 quadrant
// as 4x4 fragments of 16x16, K=256 in 8 steps of 32.
// ---------------------------------------------------------------------------
#define LDSS 264   // padded LDS row stride (bf16 elems): 264*2B=528B -> 2-way bank pattern

__global__ __launch_bounds__(256) void cos_mse(
    const __hip_bfloat16* __restrict__ Ahat,
    const float* __restrict__ S, float* __restrict__ accum)
{
    __shared__ __hip_bfloat16 Ah[128 * LDSS];
    __shared__ __hip_bfloat16 Bh[128 * LDSS];
    __shared__ float wsum[4];

    const int ti  = blockIdx.y * 128;
    const int tj  = blockIdx.x * 128;
    const int tid = threadIdx.x;

    // stage both 128x256 bf16 tiles (16B chunks, coalesced)
    #pragma unroll
    for (int it = 0; it < 16; ++it) {
        const int q = it * 256 + tid;       // 0..4095
        const int r = q >> 5;               // row in tile
        const int v = q & 31;               // 16B chunk in row
        const uint4 da = *reinterpret_cast<const uint4*>(
            Ahat + (size_t)(ti + r) * DDIM + v * 8);
        *reinterpret_cast<uint4*>(&Ah[r * LDSS + v * 8]) = da;
        const uint4 db = *reinterpret_cast<const uint4*>(
            Ahat + (size_t)(tj + r) * DDIM + v * 8);
        *reinterpret_cast<uint4*>(&Bh[r * LDSS + v * 8]) = db;
    }
    __syncthreads();

    const int w    = tid >> 6;
    const int lane = tid & 63;
    const int wr   = (w >> 1) * 64;     // wave's row offset in tile
    const int wc   = (w & 1) * 64;      // wave's col offset in tile
    const int fr   = lane & 15;         // fragment row/col
    const int kg   = lane >> 4;         // k-group (0..3), 8 elems each

    f32x4 acc[4][4] = {};

    #pragma unroll
    for (int k0 = 0; k0 < 256; k0 += 32) {
        s16x8 af[4], bfr[4];
        #pragma unroll
        for (int m = 0; m < 4; ++m)
            af[m] = *reinterpret_cast<const s16x8*>(
                &Ah[(wr + m * 16 + fr) * LDSS + k0 + kg * 8]);
        #pragma unroll
        for (int n = 0; n < 4; ++n)
            bfr[n] = *reinterpret_cast<const s16x8*>(
                &Bh[(wc + n * 16 + fr) * LDSS + k0 + kg * 8]);
        #pragma unroll
        for (int m = 0; m < 4; ++m)
            #pragma unroll
            for (int n = 0; n < 4; ++n)
                acc[m][n] = __builtin_amdgcn_mfma_f32_16x16x32_bf16(
                    af[m], bfr[n], acc[m][n], 0, 0, 0);
    }

    // fused epilogue: sum (cos - S)^2 over this 128x128 tile
    // C/D layout: col = lane&15, row = (lane>>4)*4 + reg   [m89/m91]
    float local = 0.0f;
    #pragma unroll
    for (int m = 0; m < 4; ++m) {
        #pragma unroll
        for (int reg = 0; reg < 4; ++reg) {
            const int gi = ti + wr + m * 16 + kg * 4 + reg;
            const float* srow = S + (size_t)gi * BDIM + tj + wc + fr;
            #pragma unroll
            for (int n = 0; n < 4; ++n) {
                const float d = acc[m][n][reg] - srow[n * 16];
                local += d * d;
            }
        }
    }

    #pragma unroll
    for (int off = 32; off > 0; off >>= 1)
        local += __shfl_down(local, off);
    if (lane == 0) wsum[w] = local;
    __syncthreads();
    if (tid == 0)
        atomicAdd(&accum[1], wsum[0] + wsum[1] + wsum[2] + wsum[3]);
}

// ---------------------------------------------------------------------------
// finalize: out = triplet_sum/B + sim_sum/B^2
// ---------------------------------------------------------------------------
__global__ void finalize(const float* __restrict__ accum, float* __restrict__ out) {
    out[0] = accum[0] * (1.0f / (float)BDIM)
           + accum[1] * (1.0f / ((float)BDIM * (float)BDIM));
}

extern "C" void kernel_launch(void* const* d_in, const int* in_sizes, int n_in,
                              void* d_out, int out_size, void* d_ws, size_t ws_size,
                              hipStream_t stream)
{
    const float* anchor   = (const float*)d_in[0];
    const float* positive = (const float*)d_in[1];
    const float* negative = (const float*)d_in[2];
    const float* S        = (const float*)d_in[3];
    float* out = (float*)d_out;

    float* accum = (float*)d_ws;                                   // [0]=trip, [1]=sim
    __hip_bfloat16* Ahat = (__hip_bfloat16*)((char*)d_ws + 256);   // 4 MB bf16 a_hat

    init_accum<<<1, 64, 0, stream>>>(accum);
    row_stats<<<BDIM / 4, 256, 0, stream>>>(anchor, positive, negative, Ahat, accum);
    dim3 grid(BDIM / 128, BDIM / 128);
    cos_mse<<<grid, 256, 0, stream>>>(Ahat, S, accum);
    finalize<<<1, 1, 0, stream>>>(accum, out);
}

// Round 2
// 214.477 us; speedup vs baseline: 1.0213x; 1.0213x over previous
//
#include <hip/hip_runtime.h>
#include <hip/hip_bf16.h>

#define BDIM 8192
#define DDIM 256

typedef __attribute__((ext_vector_type(8))) short  s16x8;   // 8 x bf16 (4 VGPRs)
typedef __attribute__((ext_vector_type(4))) float  f32x4;   // MFMA accumulator

__device__ inline ushort f2bf(float x) {
    __hip_bfloat16 h = __float2bfloat16(x);
    ushort u;
    __builtin_memcpy(&u, &h, 2);
    return u;
}

// ---------------------------------------------------------------------------
// init: zero the two accumulators in workspace
// ---------------------------------------------------------------------------
__global__ void init_accum(float* accum) {
    if (threadIdx.x < 2) accum[threadIdx.x] = 0.0f;
}

// ---------------------------------------------------------------------------
// Kernel A: per-row stats + fragment-swizzled bf16 a_hat.
// Swizzle layout (16B chunks of 8 bf16):
//   chunk_idx(row, k) = ((row>>4)*8 + k32)*64 + kg*16 + (row&15)
//   where k32 = k/32, kg = (k/8)&3. One MFMA fragment load in cos_mse then
//   reads chunks [base .. base+63] with chunk = base + lane  -> contiguous 1KB.
// ---------------------------------------------------------------------------
__global__ __launch_bounds__(256) void row_stats(
    const float* __restrict__ A, const float* __restrict__ P,
    const float* __restrict__ N, ushort* __restrict__ Asw,
    float* __restrict__ accum)
{
    const int wave = threadIdx.x >> 6;
    const int lane = threadIdx.x & 63;
    const int row  = blockIdx.x * 4 + wave;

    const float4 a = *(reinterpret_cast<const float4*>(A + (size_t)row * DDIM) + lane);
    const float4 p = *(reinterpret_cast<const float4*>(P + (size_t)row * DDIM) + lane);
    const float4 n = *(reinterpret_cast<const float4*>(N + (size_t)row * DDIM) + lane);

    float sa = a.x*a.x + a.y*a.y + a.z*a.z + a.w*a.w;

    float d0 = a.x - p.x + 1e-6f, d1 = a.y - p.y + 1e-6f;
    float d2 = a.z - p.z + 1e-6f, d3 = a.w - p.w + 1e-6f;
    float sp = d0*d0 + d1*d1 + d2*d2 + d3*d3;

    d0 = a.x - n.x + 1e-6f; d1 = a.y - n.y + 1e-6f;
    d2 = a.z - n.z + 1e-6f; d3 = a.w - n.w + 1e-6f;
    float sn = d0*d0 + d1*d1 + d2*d2 + d3*d3;

    #pragma unroll
    for (int off = 32; off > 0; off >>= 1) {
        sa += __shfl_xor(sa, off);
        sp += __shfl_xor(sp, off);
        sn += __shfl_xor(sn, off);
    }

    const float inv = 1.0f / fmaxf(sqrtf(sa), 1e-8f);

    // swizzled 8B store: lane covers cols 4*lane .. 4*lane+3
    ushort4 hv;
    hv.x = f2bf(a.x * inv);
    hv.y = f2bf(a.y * inv);
    hv.z = f2bf(a.z * inv);
    hv.w = f2bf(a.w * inv);
    const size_t chunk = ((size_t)(row >> 4) * 8 + (lane >> 3)) * 64
                       + (size_t)(((lane >> 1) & 3) * 16 + (row & 15));
    *reinterpret_cast<ushort4*>(Asw + chunk * 8 + (lane & 1) * 4) = hv;

    if (lane == 0) {
        const float t = fmaxf(sqrtf(sp) - sqrtf(sn) + 0.2f, 0.0f);
        atomicAdd(&accum[0], t);
    }
}

// ---------------------------------------------------------------------------
// Kernel B: 128x128 tile of cos = a_hat @ a_hat^T via bf16 MFMA, no LDS.
// Fragments loaded directly from the swizzled a_hat (L2/L3-resident, 1KB
// coalesced per load). Fused (cos - S)^2 reduction -> atomicAdd accum[1].
// 4 waves in 2x2; each wave a 64x64 quadrant (4x4 frags of 16x16, K=256).
// ---------------------------------------------------------------------------
__global__ __launch_bounds__(256) void cos_mse(
    const ushort* __restrict__ Asw,
    const float* __restrict__ S, float* __restrict__ accum)
{
    __shared__ float wsum[4];

    const int tid  = threadIdx.x;
    const int w    = tid >> 6;
    const int lane = tid & 63;
    const int ti   = blockIdx.y * 128;
    const int tj   = blockIdx.x * 128;
    const int wr   = (w >> 1) * 64;
    const int wc   = (w & 1) * 64;
    const int fr   = lane & 15;
    const int kg   = lane >> 4;

    // base: ((rowblk)*8 + k32)*64 chunks of 8 ushorts; lane-linear within group
    const ushort* ab = Asw + (size_t)((ti + wr) >> 4) * 4096 + (size_t)lane * 8;
    const ushort* bb = Asw + (size_t)((tj + wc) >> 4) * 4096 + (size_t)lane * 8;
    // m (+16 rows) stride = 4096 ushorts, k32 stride = 512 ushorts

    f32x4 acc[4][4] = {};

    #pragma unroll
    for (int k32 = 0; k32 < 8; ++k32) {
        s16x8 af[4], bf4[4];
        #pragma unroll
        for (int m = 0; m < 4; ++m)
            af[m] = *reinterpret_cast<const s16x8*>(ab + m * 4096 + k32 * 512);
        #pragma unroll
        for (int n = 0; n < 4; ++n)
            bf4[n] = *reinterpret_cast<const s16x8*>(bb + n * 4096 + k32 * 512);
        #pragma unroll
        for (int m = 0; m < 4; ++m)
            #pragma unroll
            for (int n = 0; n < 4; ++n)
                acc[m][n] = __builtin_amdgcn_mfma_f32_16x16x32_bf16(
                    af[m], bf4[n], acc[m][n], 0, 0, 0);
    }

    // fused epilogue: sum (cos - S)^2 over this 128x128 tile
    // C/D layout: col = lane&15, row = (lane>>4)*4 + reg   [m89/m91]
    float local = 0.0f;
    #pragma unroll
    for (int m = 0; m < 4; ++m) {
        #pragma unroll
        for (int reg = 0; reg < 4; ++reg) {
            const int gi = ti + wr + m * 16 + kg * 4 + reg;
            const float* srow = S + (size_t)gi * BDIM + tj + wc + fr;
            #pragma unroll
            for (int n = 0; n < 4; ++n) {
                const float d = acc[m][n][reg] - srow[n * 16];
                local += d * d;
            }
        }
    }

    #pragma unroll
    for (int off = 32; off > 0; off >>= 1)
        local += __shfl_down(local, off);
    if (lane == 0) wsum[w] = local;
    __syncthreads();
    if (tid == 0)
        atomicAdd(&accum[1], wsum[0] + wsum[1] + wsum[2] + wsum[3]);
}

// ---------------------------------------------------------------------------
// finalize: out = triplet_sum/B + sim_sum/B^2
// ---------------------------------------------------------------------------
__global__ void finalize(const float* __restrict__ accum, float* __restrict__ out) {
    out[0] = accum[0] * (1.0f / (float)BDIM)
           + accum[1] * (1.0f / ((float)BDIM * (float)BDIM));
}

extern "C" void kernel_launch(void* const* d_in, const int* in_sizes, int n_in,
                              void* d_out, int out_size, void* d_ws, size_t ws_size,
                              hipStream_t stream)
{
    const float* anchor   = (const float*)d_in[0];
    const float* positive = (const float*)d_in[1];
    const float* negative = (const float*)d_in[2];
    const float* S        = (const float*)d_in[3];
    float* out = (float*)d_out;

    float* accum = (float*)d_ws;                          // [0]=trip, [1]=sim
    ushort* Asw  = (ushort*)((char*)d_ws + 256);          // 4 MB swizzled bf16 a_hat

    init_accum<<<1, 64, 0, stream>>>(accum);
    row_stats<<<BDIM / 4, 256, 0, stream>>>(anchor, positive, negative, Asw, accum);
    dim3 grid(BDIM / 128, BDIM / 128);
    cos_mse<<<grid, 256, 0, stream>>>(Asw, S, accum);
    finalize<<<1, 1, 0, stream>>>(accum, out);
}

// Round 3
// 111.919 us; speedup vs baseline: 1.9572x; 1.9164x over previous
//
#include <hip/hip_runtime.h>
#include <hip/hip_bf16.h>

#define BDIM 8192
#define DDIM 256

typedef __attribute__((ext_vector_type(8))) short  s16x8;   // 8 x bf16 (4 VGPRs)
typedef __attribute__((ext_vector_type(4))) float  f32x4;   // MFMA accumulator

#define GLOBAL_AS __attribute__((address_space(1)))
#define LDS_AS    __attribute__((address_space(3)))

__device__ __forceinline__ void stage16(const float* g, float* l) {
    // 16 B per lane, LDS dest = wave-uniform base + lane*16 (linear)
    __builtin_amdgcn_global_load_lds((const GLOBAL_AS unsigned int*)g,
                                     (LDS_AS unsigned int*)l, 16, 0, 0);
}

__device__ inline ushort f2bf(float x) {
    __hip_bfloat16 h = __float2bfloat16(x);
    ushort u;
    __builtin_memcpy(&u, &h, 2);
    return u;
}

// ---------------------------------------------------------------------------
// Kernel A: per-row stats + fragment-swizzled bf16 a_hat.
//   chunk_idx(row, k) = ((row>>4)*8 + k32)*64 + kg*16 + (row&15),
//   k32 = k/32, kg = (k/8)&3. A fragment load in cos_mse reads chunks
//   [base .. base+63] with chunk = base + lane -> contiguous 1KB.
// Triplet partial -> partial_trip[block] (no atomics).
// ---------------------------------------------------------------------------
__global__ __launch_bounds__(256) void row_stats(
    const float* __restrict__ A, const float* __restrict__ P,
    const float* __restrict__ N, ushort* __restrict__ Asw,
    float* __restrict__ partial_trip)
{
    __shared__ float tsh[4];
    const int wave = threadIdx.x >> 6;
    const int lane = threadIdx.x & 63;
    const int row  = blockIdx.x * 4 + wave;

    const float4 a = *(reinterpret_cast<const float4*>(A + (size_t)row * DDIM) + lane);
    const float4 p = *(reinterpret_cast<const float4*>(P + (size_t)row * DDIM) + lane);
    const float4 n = *(reinterpret_cast<const float4*>(N + (size_t)row * DDIM) + lane);

    float sa = a.x*a.x + a.y*a.y + a.z*a.z + a.w*a.w;

    float d0 = a.x - p.x + 1e-6f, d1 = a.y - p.y + 1e-6f;
    float d2 = a.z - p.z + 1e-6f, d3 = a.w - p.w + 1e-6f;
    float sp = d0*d0 + d1*d1 + d2*d2 + d3*d3;

    d0 = a.x - n.x + 1e-6f; d1 = a.y - n.y + 1e-6f;
    d2 = a.z - n.z + 1e-6f; d3 = a.w - n.w + 1e-6f;
    float sn = d0*d0 + d1*d1 + d2*d2 + d3*d3;

    #pragma unroll
    for (int off = 32; off > 0; off >>= 1) {
        sa += __shfl_xor(sa, off);
        sp += __shfl_xor(sp, off);
        sn += __shfl_xor(sn, off);
    }

    const float inv = 1.0f / fmaxf(sqrtf(sa), 1e-8f);

    ushort4 hv;
    hv.x = f2bf(a.x * inv);
    hv.y = f2bf(a.y * inv);
    hv.z = f2bf(a.z * inv);
    hv.w = f2bf(a.w * inv);
    const size_t chunk = ((size_t)(row >> 4) * 8 + (lane >> 3)) * 64
                       + (size_t)(((lane >> 1) & 3) * 16 + (row & 15));
    *reinterpret_cast<ushort4*>(Asw + chunk * 8 + (lane & 1) * 4) = hv;

    if (lane == 0)
        tsh[wave] = fmaxf(sqrtf(sp) - sqrtf(sn) + 0.2f, 0.0f);
    __syncthreads();
    if (threadIdx.x == 0)
        partial_trip[blockIdx.x] = tsh[0] + tsh[1] + tsh[2] + tsh[3];
}

// ---------------------------------------------------------------------------
// Kernel B: 128x128 tile of cos = a_hat @ a_hat^T (bf16 MFMA), fused MSE.
// Phase 1: fire-and-forget stage of the S tile (64KB fp32) into LDS via
//          global_load_lds — issued BEFORE compute so HBM streams under MFMA.
// Phase 2: MFMA with fragments direct from L2 (swizzled a_hat, 1KB/load),
//          unroll capped at 2 to keep <=16 loads in flight (no spill).
// Phase 3: __syncthreads (drains vmcnt) -> epilogue reads S from LDS.
// Per-block partial -> partial_sim[block] (no atomics).
// ---------------------------------------------------------------------------
__global__ __launch_bounds__(256) void cos_mse(
    const ushort* __restrict__ Asw,
    const float* __restrict__ S, float* __restrict__ partial_sim)
{
    __shared__ float s_tile[128 * 128];   // 64 KB
    __shared__ float wsum[4];

    const int tid  = threadIdx.x;
    const int w    = tid >> 6;
    const int lane = tid & 63;

    // XCD-aware swizzle: 4096 blocks, 8 XCDs -> 512 contiguous tiles each
    const int bid = blockIdx.x;
    const int swz = (bid & 7) * 512 + (bid >> 3);
    const int ti  = (swz >> 6) * 128;
    const int tj  = (swz & 63) * 128;

    // ---- Phase 1: issue S staging (each wave: 2 rows per round, 16 rounds)
    {
        const int rhalf = lane >> 5;          // 0/1: which of the 2 rows
        const int col16 = lane & 31;          // 16B chunk within the row
        const float* gsrc = S + (size_t)(ti + w * 2 + rhalf) * BDIM + tj + col16 * 4;
        #pragma unroll
        for (int it = 0; it < 16; ++it)
            stage16(gsrc + (size_t)it * 8 * BDIM, &s_tile[(it * 8 + w * 2) * 128]);
    }

    // ---- Phase 2: MFMA from swizzled a_hat (L2-resident)
    const int wr = (w >> 1) * 64;
    const int wc = (w & 1) * 64;
    const int fr = lane & 15;
    const int kg = lane >> 4;

    const ushort* ab = Asw + (size_t)((ti + wr) >> 4) * 4096 + (size_t)lane * 8;
    const ushort* bb = Asw + (size_t)((tj + wc) >> 4) * 4096 + (size_t)lane * 8;

    f32x4 acc[4][4] = {};

    #pragma unroll 2
    for (int k32 = 0; k32 < 8; ++k32) {
        s16x8 af[4], bf4[4];
        #pragma unroll
        for (int m = 0; m < 4; ++m)
            af[m] = *reinterpret_cast<const s16x8*>(ab + m * 4096 + k32 * 512);
        #pragma unroll
        for (int n = 0; n < 4; ++n)
            bf4[n] = *reinterpret_cast<const s16x8*>(bb + n * 4096 + k32 * 512);
        #pragma unroll
        for (int m = 0; m < 4; ++m)
            #pragma unroll
            for (int n = 0; n < 4; ++n)
                acc[m][n] = __builtin_amdgcn_mfma_f32_16x16x32_bf16(
                    af[m], bf4[n], acc[m][n], 0, 0, 0);
    }

    // ---- Phase 3: staged S is visible after the barrier (vmcnt drained)
    __syncthreads();

    // C/D layout: col = lane&15, row = (lane>>4)*4 + reg   [m89/m91]
    float local = 0.0f;
    #pragma unroll
    for (int m = 0; m < 4; ++m) {
        #pragma unroll
        for (int reg = 0; reg < 4; ++reg) {
            const int lr = wr + m * 16 + kg * 4 + reg;   // row within tile
            #pragma unroll
            for (int n = 0; n < 4; ++n) {
                const float d = acc[m][n][reg] - s_tile[lr * 128 + wc + n * 16 + fr];
                local += d * d;
            }
        }
    }

    #pragma unroll
    for (int off = 32; off > 0; off >>= 1)
        local += __shfl_down(local, off);
    if (lane == 0) wsum[w] = local;
    __syncthreads();
    if (tid == 0)
        partial_sim[bid] = wsum[0] + wsum[1] + wsum[2] + wsum[3];
}

// ---------------------------------------------------------------------------
// finalize: out = sum(partial_trip)/B + sum(partial_sim)/B^2
// ---------------------------------------------------------------------------
__global__ __launch_bounds__(256) void finalize(
    const float* __restrict__ pt, const float* __restrict__ ps,
    float* __restrict__ out)
{
    __shared__ float sh[4];
    float v = 0.0f;
    for (int i = threadIdx.x; i < 2048; i += 256) v += pt[i] * (1.0f / (float)BDIM);
    for (int i = threadIdx.x; i < 4096; i += 256)
        v += ps[i] * (1.0f / ((float)BDIM * (float)BDIM));
    #pragma unroll
    for (int off = 32; off > 0; off >>= 1) v += __shfl_down(v, off);
    const int w = threadIdx.x >> 6, lane = threadIdx.x & 63;
    if (lane == 0) sh[w] = v;
    __syncthreads();
    if (threadIdx.x == 0) out[0] = sh[0] + sh[1] + sh[2] + sh[3];
}

extern "C" void kernel_launch(void* const* d_in, const int* in_sizes, int n_in,
                              void* d_out, int out_size, void* d_ws, size_t ws_size,
                              hipStream_t stream)
{
    const float* anchor   = (const float*)d_in[0];
    const float* positive = (const float*)d_in[1];
    const float* negative = (const float*)d_in[2];
    const float* S        = (const float*)d_in[3];
    float* out = (float*)d_out;

    float*  partial_trip = (float*)d_ws;                       // 2048 floats
    float*  partial_sim  = (float*)d_ws + 2048;                // 4096 floats
    ushort* Asw          = (ushort*)((char*)d_ws + 32768);     // 4 MB swizzled a_hat

    row_stats<<<BDIM / 4, 256, 0, stream>>>(anchor, positive, negative, Asw, partial_trip);
    cos_mse<<<4096, 256, 0, stream>>>(Asw, S, partial_sim);
    finalize<<<1, 256, 0, stream>>>(partial_trip, partial_sim, out);
}

// Round 4
// 100.419 us; speedup vs baseline: 2.1813x; 1.1145x over previous
//
#include <hip/hip_runtime.h>
#include <hip/hip_bf16.h>

#define BDIM 8192
#define DDIM 256

typedef __attribute__((ext_vector_type(8))) short  s16x8;   // 8 x bf16 (4 VGPRs)
typedef __attribute__((ext_vector_type(4))) float  f32x4;   // MFMA accumulator

#define GLOBAL_AS __attribute__((address_space(1)))
#define LDS_AS    __attribute__((address_space(3)))

// 16B/lane fire-and-forget global->LDS, NT (non-temporal) cache policy so the
// 268 MB S stream does not evict the 4 MB a_hat working set from per-XCD L2.
__device__ __forceinline__ void stage16nt(const float* g, float* l) {
    __builtin_amdgcn_global_load_lds((const GLOBAL_AS unsigned int*)g,
                                     (LDS_AS unsigned int*)l, 16, 0, 2 /*NT*/);
}

__device__ inline ushort f2bf(float x) {
    __hip_bfloat16 h = __float2bfloat16(x);
    ushort u;
    __builtin_memcpy(&u, &h, 2);
    return u;
}

// ---------------------------------------------------------------------------
// Kernel A: per-row stats + fragment-swizzled bf16 a_hat.
//   chunk_idx(row, k) = ((row>>4)*8 + k32)*64 + kg*16 + (row&15),
//   k32 = k/32, kg = (k/8)&3. A fragment load in cos_mse reads chunks
//   [base .. base+63] with chunk = base + lane -> contiguous 1KB.
// ---------------------------------------------------------------------------
__global__ __launch_bounds__(256) void row_stats(
    const float* __restrict__ A, const float* __restrict__ P,
    const float* __restrict__ N, ushort* __restrict__ Asw,
    float* __restrict__ partial_trip)
{
    __shared__ float tsh[4];
    const int wave = threadIdx.x >> 6;
    const int lane = threadIdx.x & 63;
    const int row  = blockIdx.x * 4 + wave;

    const float4 a = *(reinterpret_cast<const float4*>(A + (size_t)row * DDIM) + lane);
    const float4 p = *(reinterpret_cast<const float4*>(P + (size_t)row * DDIM) + lane);
    const float4 n = *(reinterpret_cast<const float4*>(N + (size_t)row * DDIM) + lane);

    float sa = a.x*a.x + a.y*a.y + a.z*a.z + a.w*a.w;

    float d0 = a.x - p.x + 1e-6f, d1 = a.y - p.y + 1e-6f;
    float d2 = a.z - p.z + 1e-6f, d3 = a.w - p.w + 1e-6f;
    float sp = d0*d0 + d1*d1 + d2*d2 + d3*d3;

    d0 = a.x - n.x + 1e-6f; d1 = a.y - n.y + 1e-6f;
    d2 = a.z - n.z + 1e-6f; d3 = a.w - n.w + 1e-6f;
    float sn = d0*d0 + d1*d1 + d2*d2 + d3*d3;

    #pragma unroll
    for (int off = 32; off > 0; off >>= 1) {
        sa += __shfl_xor(sa, off);
        sp += __shfl_xor(sp, off);
        sn += __shfl_xor(sn, off);
    }

    const float inv = 1.0f / fmaxf(sqrtf(sa), 1e-8f);

    ushort4 hv;
    hv.x = f2bf(a.x * inv);
    hv.y = f2bf(a.y * inv);
    hv.z = f2bf(a.z * inv);
    hv.w = f2bf(a.w * inv);
    const size_t chunk = ((size_t)(row >> 4) * 8 + (lane >> 3)) * 64
                       + (size_t)(((lane >> 1) & 3) * 16 + (row & 15));
    *reinterpret_cast<ushort4*>(Asw + chunk * 8 + (lane & 1) * 4) = hv;

    if (lane == 0)
        tsh[wave] = fmaxf(sqrtf(sp) - sqrtf(sn) + 0.2f, 0.0f);
    __syncthreads();
    if (threadIdx.x == 0)
        partial_trip[blockIdx.x] = tsh[0] + tsh[1] + tsh[2] + tsh[3];
}

// ---------------------------------------------------------------------------
// Kernel B (persistent): 512 blocks (2/CU), each owns 8 tiles of 128x128 with
// CONSTANT ti -> A-panel fragments live in registers across all 8 tiles
// (halves fragment traffic; B-panel-only reads stay L2-hot thanks to NT on S).
// Per tile: stage S (64KB LDS, NT) -> MFMA (af resident, bf from L2) ->
// barrier -> fused (cos-S)^2 from LDS -> per-wave partial -> barrier.
// Cross-block TLP (2 blocks/CU) overlaps one block's stage with the other's
// compute.
// ---------------------------------------------------------------------------
__global__ __launch_bounds__(256, 2) void cos_mse(
    const ushort* __restrict__ Asw,
    const float* __restrict__ S,
    float* __restrict__ partial_sim)
{
    __shared__ float s_tile[128 * 128];   // 64 KB

    const int tid  = threadIdx.x;
    const int w    = tid >> 6;
    const int lane = tid & 63;

    // XCD-aware persistent mapping: xcd = b&7 gets a contiguous 512-run of
    // tile indices; each block's 8 tiles share one ti band (A reuse).
    const int b   = blockIdx.x;           // 0..511
    const int xcd = b & 7;
    const int q   = b >> 3;               // 0..63
    const int ti  = (xcd * 8 + (q >> 3)) * 128;   // constant per block

    const int wr    = (w >> 1) * 64;
    const int wc    = (w & 1) * 64;
    const int fr    = lane & 15;
    const int kg    = lane >> 4;
    const int rhalf = lane >> 5;
    const int col16 = lane & 31;

    // resident A-panel fragments: af[k32*4+m], 32 x s16x8 = 128 VGPR
    s16x8 af[32];
    {
        const ushort* ab = Asw + (size_t)((ti + wr) >> 4) * 4096 + (size_t)lane * 8;
        #pragma unroll
        for (int k32 = 0; k32 < 8; ++k32)
            #pragma unroll
            for (int m = 0; m < 4; ++m)
                af[k32 * 4 + m] = *reinterpret_cast<const s16x8*>(
                    ab + (size_t)m * 4096 + k32 * 512);
    }

    for (int i = 0; i < 8; ++i) {
        const int tj = ((q & 7) * 8 + i) * 128;

        // ---- stage this tile's S (fire-and-forget, NT)
        {
            const float* gsrc = S + (size_t)(ti + w * 2 + rhalf) * BDIM + tj + col16 * 4;
            #pragma unroll
            for (int it = 0; it < 16; ++it)
                stage16nt(gsrc + (size_t)it * 8 * BDIM,
                          &s_tile[(it * 8 + w * 2) * 128]);
        }

        // ---- MFMA: af resident, bf streamed from L2
        f32x4 acc[4][4] = {};
        const ushort* bb = Asw + (size_t)((tj + wc) >> 4) * 4096 + (size_t)lane * 8;
        #pragma unroll
        for (int k32 = 0; k32 < 8; ++k32) {
            s16x8 bf4[4];
            #pragma unroll
            for (int n = 0; n < 4; ++n)
                bf4[n] = *reinterpret_cast<const s16x8*>(
                    bb + (size_t)n * 4096 + k32 * 512);
            #pragma unroll
            for (int m = 0; m < 4; ++m)
                #pragma unroll
                for (int n = 0; n < 4; ++n)
                    acc[m][n] = __builtin_amdgcn_mfma_f32_16x16x32_bf16(
                        af[k32 * 4 + m], bf4[n], acc[m][n], 0, 0, 0);
        }

        __syncthreads();   // stage drained (vmcnt0) + all waves aligned

        // ---- fused epilogue from LDS
        // C/D layout: col = lane&15, row = (lane>>4)*4 + reg
        float local = 0.0f;
        #pragma unroll
        for (int m = 0; m < 4; ++m)
            #pragma unroll
            for (int reg = 0; reg < 4; ++reg) {
                const int lr = wr + m * 16 + kg * 4 + reg;
                #pragma unroll
                for (int n = 0; n < 4; ++n) {
                    const float d = acc[m][n][reg]
                                  - s_tile[lr * 128 + wc + n * 16 + fr];
                    local += d * d;
                }
            }

        #pragma unroll
        for (int off = 32; off > 0; off >>= 1)
            local += __shfl_down(local, off);
        if (lane == 0)
            partial_sim[(size_t)(xcd * 512 + q * 8 + i) * 4 + w] = local;

        __syncthreads();   // epilogue reads done before next tile's stage
    }
}

// ---------------------------------------------------------------------------
// finalize: out = sum(partial_trip)/B + sum(partial_sim)/B^2
// ---------------------------------------------------------------------------
__global__ __launch_bounds__(256) void finalize(
    const float* __restrict__ pt, const float* __restrict__ ps,
    float* __restrict__ out)
{
    __shared__ float sh[4];
    float v = 0.0f;
    for (int i = threadIdx.x; i < 2048; i += 256)
        v += pt[i] * (1.0f / (float)BDIM);
    for (int i = threadIdx.x; i < 16384; i += 256)
        v += ps[i] * (1.0f / ((float)BDIM * (float)BDIM));
    #pragma unroll
    for (int off = 32; off > 0; off >>= 1) v += __shfl_down(v, off);
    const int w = threadIdx.x >> 6, lane = threadIdx.x & 63;
    if (lane == 0) sh[w] = v;
    __syncthreads();
    if (threadIdx.x == 0) out[0] = sh[0] + sh[1] + sh[2] + sh[3];
}

extern "C" void kernel_launch(void* const* d_in, const int* in_sizes, int n_in,
                              void* d_out, int out_size, void* d_ws, size_t ws_size,
                              hipStream_t stream)
{
    const float* anchor   = (const float*)d_in[0];
    const float* positive = (const float*)d_in[1];
    const float* negative = (const float*)d_in[2];
    const float* S        = (const float*)d_in[3];
    float* out = (float*)d_out;

    float*  partial_trip = (float*)d_ws;                        // 2048 floats
    float*  partial_sim  = (float*)((char*)d_ws + 8192);        // 16384 floats
    ushort* Asw          = (ushort*)((char*)d_ws + 131072);     // 4 MB swizzled a_hat

    row_stats<<<BDIM / 4, 256, 0, stream>>>(anchor, positive, negative, Asw, partial_trip);
    cos_mse<<<512, 256, 0, stream>>>(Asw, S, partial_sim);
    finalize<<<1, 256, 0, stream>>>(partial_trip, partial_sim, out);
}